// Round 2
// baseline (687.480 us; speedup 1.0000x reference)
//
#include <hip/hip_runtime.h>
#include <math.h>

#define NB    2048
#define NTOK  49
#define CH    768
#define MID   48
#define K1    36
#define K2    24

__device__ __forceinline__ float wsum(float v) {
    #pragma unroll
    for (int off = 32; off; off >>= 1) v += __shfl_xor(v, off, 64);
    return v;
}
__device__ __forceinline__ float gelu_exact(float v) {
    return 0.5f * v * (1.0f + erff(v * 0.70710678118654752440f));
}
__device__ __forceinline__ float sigmoidf(float v) {
    return 1.0f / (1.0f + expf(-v));
}

// ---------------- KA: per-batch column SUMS (not means) ----------------
// grid 2048 x 384thr. Reads x once (308 MB, BW-bound), writes colsum [2048,768].
__global__ __launch_bounds__(384)
void ka_colsum(const float* __restrict__ x, float* __restrict__ colsum)
{
    __shared__ float4 part[2][192];
    const int tid = threadIdx.x;
    const int c4 = tid % 192;      // float4 column group
    const int n0 = tid / 192;      // row parity
    const int b  = blockIdx.x;
    const float4* xb = (const float4*)(x + (size_t)b * (NTOK*CH));
    float4 acc = {0.f,0.f,0.f,0.f};
    for (int n = n0; n < NTOK; n += 2) {
        float4 v = xb[n*192 + c4];
        acc.x += v.x; acc.y += v.y; acc.z += v.z; acc.w += v.w;
    }
    part[n0][c4] = acc;
    __syncthreads();
    if (tid < 192) {
        float4 a = part[0][tid], q = part[1][tid];
        float4 r; r.x=a.x+q.x; r.y=a.y+q.y; r.z=a.z+q.z; r.w=a.w+q.w;
        ((float4*)colsum)[(size_t)b*192 + tid] = r;
    }
}

// ---------------- KB/KE: h = gelu(sin@W1*scale + b1) ----------------
// grid 256 x 384thr, 8 batches/block. scale = 1/49 (round1, sin=colsum) or 1 (round2, sin=s2 mean).
__global__ __launch_bounds__(384)
void kb_gemv1(const float* __restrict__ sin, const float* __restrict__ w1,
              const float* __restrict__ b1, float* __restrict__ h, float scale)
{
    __shared__ float lds_s[8][772];   // +4 pad: bank-decorrelate the 8 batch rows
    const int tid = threadIdx.x;
    const int base = blockIdx.x * 8;
    #pragma unroll
    for (int k = 0; k < 4; ++k) {
        int i = tid + 384*k;          // 0..1535
        int bb = i / 192, c4 = i % 192;
        float4 v = ((const float4*)sin)[(size_t)(base+bb)*192 + c4];
        *(float4*)&lds_s[bb][4*c4] = v;
    }
    __syncthreads();
    const int m  = tid % MID;
    const int bg = tid / MID;         // 0..7
    float acc = 0.f;
    #pragma unroll 8
    for (int c = 0; c < CH; ++c)
        acc = fmaf(lds_s[bg][c], w1[c*MID + m], acc);
    h[(size_t)(base+bg)*MID + m] = gelu_exact(acc * scale + b1[m]);
}

// ---------------- KC/KF: gates = sigmoid(h@W2 + b2) [* gmul] ----------------
// grid (64,3) x 256thr: 32 batches x 256 cols per block. gmul==nullptr for round 1;
// round 2: gmul = gout = g1 buffer (in-place g12 = g1*g2, same thread RMW).
__global__ __launch_bounds__(256)
void kc_gemv2(const float* __restrict__ h, const float* __restrict__ w2,
              const float* __restrict__ b2, const float* __restrict__ gmul,
              float* __restrict__ gout)
{
    __shared__ float lh[32][MID];
    const int tid  = threadIdx.x;
    const int base = blockIdx.x * 32;
    const int c    = blockIdx.y * 256 + tid;
    #pragma unroll
    for (int k = 0; k < 6; ++k) {
        int i = tid + 256*k;          // 0..1535
        int bb = i / MID, m = i % MID;
        lh[bb][m] = h[(size_t)(base+bb)*MID + m];
    }
    __syncthreads();
    float wr[MID];
    #pragma unroll
    for (int m = 0; m < MID; ++m) wr[m] = w2[(size_t)m*CH + c];
    const float bias = b2[c];
    for (int bb = 0; bb < 32; ++bb) {
        float acc = bias;
        #pragma unroll
        for (int m = 0; m < MID; ++m) acc = fmaf(lh[bb][m], wr[m], acc);
        float g = sigmoidf(acc);
        size_t o = (size_t)(base+bb)*CH + c;
        gout[o] = gmul ? gmul[o] * g : g;
    }
}

// ---------------- KD: gated row norms -> top-36 -> s2 = g1 * mean(sel rows) ----
// grid 2048 x 512thr, REVERSE batch order (anti-LRU: L3 tail from KA becomes hits).
__global__ __launch_bounds__(512)
void kd_norm_select(const float* __restrict__ x, const float* __restrict__ g1,
                    float* __restrict__ s2, int* __restrict__ sel1g)
{
    __shared__ float g1v[CH];
    __shared__ float gsq[CH];
    __shared__ float ts[64];
    __shared__ int   seln[K1];
    const int tid = threadIdx.x, lane = tid & 63, wv = tid >> 6;
    const int b = NB - 1 - blockIdx.x;
    const float* xb = x + (size_t)b * (NTOK*CH);

    for (int c = tid; c < CH; c += 512) {
        float g = g1[(size_t)b*CH + c];
        g1v[c] = g; gsq[c] = g*g;
    }
    __syncthreads();

    // cache this lane's 12 gsq values (cols 4*lane + 256k + j)
    float gs[12];
    #pragma unroll
    for (int k = 0; k < 3; ++k) {
        float4 q = *(const float4*)&gsq[4*lane + 256*k];
        gs[4*k+0]=q.x; gs[4*k+1]=q.y; gs[4*k+2]=q.z; gs[4*k+3]=q.w;
    }

    for (int n = wv; n < NTOK; n += 8) {
        const float4* row = (const float4*)(xb + n*CH);
        float acc = 0.f;
        #pragma unroll
        for (int k = 0; k < 3; ++k) {
            float4 v = row[lane + 64*k];
            acc = fmaf(v.x*v.x, gs[4*k+0], acc);
            acc = fmaf(v.y*v.y, gs[4*k+1], acc);
            acc = fmaf(v.z*v.z, gs[4*k+2], acc);
            acc = fmaf(v.w*v.w, gs[4*k+3], acc);
        }
        acc = wsum(acc);
        if (lane == 0) ts[n] = sqrtf(acc);
    }
    __syncthreads();

    if (wv == 0) {
        float vl = (lane < NTOK) ? ts[lane] : -1.0f;
        int rank = 0;
        for (int j = 0; j < NTOK; ++j) {
            float vj = ts[j];
            rank += (vj > vl) || (vj == vl && j < lane);
        }
        if (lane < NTOK && rank < K1) { seln[rank] = lane; sel1g[(size_t)b*K1 + rank] = lane; }
    }
    __syncthreads();

    // s2 = g1 * mean of 36 selected rows (rows warm in L2/L3 from norm pass)
    int rows[K1];
    #pragma unroll
    for (int r = 0; r < K1; ++r) rows[r] = seln[r]*CH;
    for (int c = tid; c < CH; c += 512) {
        float a0=0.f, a1=0.f;
        #pragma unroll
        for (int r = 0; r < K1; r += 2) { a0 += xb[rows[r]+c]; a1 += xb[rows[r+1]+c]; }
        s2[(size_t)b*CH + c] = (a0+a1) * (1.0f/K1) * g1v[c];
    }
}

// ---------------- KG: round-2 norms on sel1 rows -> top-24 -> pool -> LN -> cls ---
// grid 2048 x 512thr, forward order (KD ended touching low batches -> L3 hits).
__global__ __launch_bounds__(512)
void kg_final(const float* __restrict__ x, const float* __restrict__ g12,
              const int* __restrict__ sel1g,
              const float* __restrict__ lng, const float* __restrict__ lnb,
              const float* __restrict__ cw,  const float* __restrict__ cb,
              float* __restrict__ out)
{
    __shared__ float g12v[CH];
    __shared__ float pooled[CH];
    __shared__ float ts2[K1];
    __shared__ int   nrow[K1];
    __shared__ int   selrows[K2];
    __shared__ float scal[2];
    const int tid = threadIdx.x, lane = tid & 63, wv = tid >> 6;
    const int b = blockIdx.x;
    const float* xb = x + (size_t)b * (NTOK*CH);

    for (int c = tid; c < CH; c += 512) g12v[c] = g12[(size_t)b*CH + c];
    if (tid < K1) nrow[tid] = sel1g[(size_t)b*K1 + tid];
    __syncthreads();

    float gr[12];
    #pragma unroll
    for (int k = 0; k < 3; ++k) {
        float4 q = *(const float4*)&g12v[4*lane + 256*k];
        gr[4*k+0]=q.x; gr[4*k+1]=q.y; gr[4*k+2]=q.z; gr[4*k+3]=q.w;
    }

    for (int j = wv; j < K1; j += 8) {
        const float4* row = (const float4*)(xb + nrow[j]*CH);
        float acc = 0.f;
        #pragma unroll
        for (int k = 0; k < 3; ++k) {
            float4 v = row[lane + 64*k];
            acc = fmaf(v.x*v.x, gr[4*k+0]*gr[4*k+0], acc);
            acc = fmaf(v.y*v.y, gr[4*k+1]*gr[4*k+1], acc);
            acc = fmaf(v.z*v.z, gr[4*k+2]*gr[4*k+2], acc);
            acc = fmaf(v.w*v.w, gr[4*k+3]*gr[4*k+3], acc);
        }
        acc = wsum(acc);
        if (lane == 0) ts2[j] = sqrtf(acc);
    }
    __syncthreads();

    if (wv == 0) {
        float vl = (lane < K1) ? ts2[lane] : -1.0f;
        int rank = 0;
        for (int j = 0; j < K1; ++j) {
            float vj = ts2[j];
            rank += (vj > vl) || (vj == vl && j < lane);
        }
        if (lane < K1 && rank < K2) selrows[rank] = nrow[lane];
    }
    __syncthreads();

    int rows[K2];
    #pragma unroll
    for (int r = 0; r < K2; ++r) rows[r] = selrows[r]*CH;
    for (int c = tid; c < CH; c += 512) {
        float a0=0.f, a1=0.f;
        #pragma unroll
        for (int r = 0; r < K2; r += 2) { a0 += xb[rows[r]+c]; a1 += xb[rows[r+1]+c]; }
        pooled[c] = (a0+a1) * (1.0f/K2) * g12v[c];
    }
    __syncthreads();

    if (wv == 0) {
        float s = 0.f, q = 0.f;
        #pragma unroll
        for (int k = 0; k < CH/64; ++k) {
            float v = pooled[lane + 64*k];
            s += v; q = fmaf(v, v, q);
        }
        s = wsum(s); q = wsum(q);
        if (lane == 0) {
            float mu  = s * (1.0f/CH);
            float var = q * (1.0f/CH) - mu*mu;
            scal[0] = mu;
            scal[1] = rsqrtf(var + 1e-5f);
        }
    }
    __syncthreads();

    if (wv < 5) {
        const float mu = scal[0], inv = scal[1];
        float acc = 0.f;
        #pragma unroll
        for (int k = 0; k < CH/64; ++k) {
            int c = lane + 64*k;
            float nv = (pooled[c] - mu) * inv * lng[c] + lnb[c];
            acc = fmaf(nv, cw[c*5 + wv], acc);
        }
        acc = wsum(acc);
        if (lane == 0) out[(size_t)b*5 + wv] = acc + cb[wv];
    }
}

// =================== Fallback: round-1 monolith (known-correct) ===================
#define NTHR 512
#define NWAVE (NTHR/64)
__global__ __launch_bounds__(NTHR, 2)
void hier_se_fused(const float* __restrict__ x,
                   const float* __restrict__ w1a, const float* __restrict__ b1a,
                   const float* __restrict__ w2a, const float* __restrict__ b2a,
                   const float* __restrict__ w1b, const float* __restrict__ b1b,
                   const float* __restrict__ w2b, const float* __restrict__ b2b,
                   const float* __restrict__ lng, const float* __restrict__ lnb,
                   const float* __restrict__ cw,  const float* __restrict__ cb,
                   float* __restrict__ out)
{
    __shared__ __align__(16) float tok[NTOK*CH];
    __shared__ float sA[CH];
    __shared__ float g1[CH];
    __shared__ float g12[CH];
    __shared__ float hb[MID];
    __shared__ float red[NWAVE*MID];
    __shared__ float ts[64];
    __shared__ int   sel1[K1];
    __shared__ int   sel2[K2];
    __shared__ float scal[2];

    const int tid  = threadIdx.x;
    const int lane = tid & 63;
    const int wv   = tid >> 6;
    const int b    = blockIdx.x;

    {
        const float4* src = (const float4*)(x + (size_t)b * (NTOK*CH));
        float4* dst = (float4*)tok;
        #pragma unroll
        for (int k = 0; k < 19; ++k) {
            int i = k*NTHR + tid;
            if (i < NTOK*CH/4) dst[i] = src[i];
        }
    }
    float wreg[96];
    {
        const int ml = lane < MID ? lane : MID-1;
        const float* wp = w1a + (96*wv)*MID + ml;
        #pragma unroll
        for (int k = 0; k < 96; ++k) wreg[k] = wp[k*MID];
    }
    __syncthreads();

    for (int c = tid; c < CH; c += NTHR) {
        float a0 = tok[48*CH + c], a1 = 0.f;
        #pragma unroll
        for (int n = 0; n < 48; n += 2) { a0 += tok[n*CH+c]; a1 += tok[(n+1)*CH+c]; }
        sA[c] = (a0 + a1) * (1.0f/NTOK);
    }
    __syncthreads();

    {
        float a0=0.f,a1=0.f,a2=0.f,a3=0.f;
        #pragma unroll
        for (int k = 0; k < 96; k += 4) {
            a0 = fmaf(wreg[k+0], sA[96*wv+k+0], a0);
            a1 = fmaf(wreg[k+1], sA[96*wv+k+1], a1);
            a2 = fmaf(wreg[k+2], sA[96*wv+k+2], a2);
            a3 = fmaf(wreg[k+3], sA[96*wv+k+3], a3);
        }
        if (lane < MID) red[wv*MID + lane] = (a0+a1)+(a2+a3);
    }
    {
        const int ml = lane < MID ? lane : MID-1;
        const float* wp = w1b + (96*wv)*MID + ml;
        #pragma unroll
        for (int k = 0; k < 96; ++k) wreg[k] = wp[k*MID];
    }
    __syncthreads();
    if (tid < MID) {
        float v = b1a[tid];
        #pragma unroll
        for (int w = 0; w < NWAVE; ++w) v += red[w*MID + tid];
        hb[tid] = gelu_exact(v);
    }
    __syncthreads();

    for (int c = tid; c < CH; c += NTHR) {
        float a0=0.f,a1=0.f,a2=0.f,a3=0.f;
        #pragma unroll
        for (int m = 0; m < MID; m += 4) {
            a0 = fmaf(hb[m+0], w2a[(m+0)*CH + c], a0);
            a1 = fmaf(hb[m+1], w2a[(m+1)*CH + c], a1);
            a2 = fmaf(hb[m+2], w2a[(m+2)*CH + c], a2);
            a3 = fmaf(hb[m+3], w2a[(m+3)*CH + c], a3);
        }
        g1[c] = sigmoidf(b2a[c] + ((a0+a1)+(a2+a3)));
    }
    __syncthreads();

    for (int n = wv; n < NTOK; n += NWAVE) {
        float acc = 0.f;
        #pragma unroll
        for (int k = 0; k < CH/64; ++k) {
            int c = lane + k*64;
            float v = tok[n*CH + c] * g1[c];
            acc = fmaf(v, v, acc);
        }
        acc = wsum(acc);
        if (lane == 0) ts[n] = sqrtf(acc);
    }
    __syncthreads();

    if (wv == 0) {
        float vl = (lane < NTOK) ? ts[lane] : -1.0f;
        int rank = 0;
        for (int j = 0; j < NTOK; ++j) {
            float vj = ts[j];
            rank += (vj > vl) || (vj == vl && j < lane);
        }
        if (lane < NTOK && rank < K1) sel1[rank] = lane;
    }
    __syncthreads();

    {
        int rows[K1];
        #pragma unroll
        for (int r = 0; r < K1; ++r) rows[r] = sel1[r]*CH;
        for (int c = tid; c < CH; c += NTHR) {
            float a0=0.f,a1=0.f;
            #pragma unroll
            for (int r = 0; r < K1; r += 2) { a0 += tok[rows[r]+c]; a1 += tok[rows[r+1]+c]; }
            sA[c] = (a0+a1) * (1.0f/K1) * g1[c];
        }
    }
    __syncthreads();

    {
        float a0=0.f,a1=0.f,a2=0.f,a3=0.f;
        #pragma unroll
        for (int k = 0; k < 96; k += 4) {
            a0 = fmaf(wreg[k+0], sA[96*wv+k+0], a0);
            a1 = fmaf(wreg[k+1], sA[96*wv+k+1], a1);
            a2 = fmaf(wreg[k+2], sA[96*wv+k+2], a2);
            a3 = fmaf(wreg[k+3], sA[96*wv+k+3], a3);
        }
        if (lane < MID) red[wv*MID + lane] = (a0+a1)+(a2+a3);
    }
    __syncthreads();
    if (tid < MID) {
        float v = b1b[tid];
        #pragma unroll
        for (int w = 0; w < NWAVE; ++w) v += red[w*MID + tid];
        hb[tid] = gelu_exact(v);
    }
    __syncthreads();

    for (int c = tid; c < CH; c += NTHR) {
        float a0=0.f,a1=0.f,a2=0.f,a3=0.f;
        #pragma unroll
        for (int m = 0; m < MID; m += 4) {
            a0 = fmaf(hb[m+0], w2b[(m+0)*CH + c], a0);
            a1 = fmaf(hb[m+1], w2b[(m+1)*CH + c], a1);
            a2 = fmaf(hb[m+2], w2b[(m+2)*CH + c], a2);
            a3 = fmaf(hb[m+3], w2b[(m+3)*CH + c], a3);
        }
        g12[c] = g1[c] * sigmoidf(b2b[c] + ((a0+a1)+(a2+a3)));
    }
    __syncthreads();

    for (int j = wv; j < K1; j += NWAVE) {
        int base = sel1[j]*CH;
        float acc = 0.f;
        #pragma unroll
        for (int k = 0; k < CH/64; ++k) {
            int c = lane + k*64;
            float v = tok[base + c] * g12[c];
            acc = fmaf(v, v, acc);
        }
        acc = wsum(acc);
        if (lane == 0) ts[j] = sqrtf(acc);
    }
    __syncthreads();

    if (wv == 0) {
        float vl = (lane < K1) ? ts[lane] : -1.0f;
        int rank = 0;
        for (int j = 0; j < K1; ++j) {
            float vj = ts[j];
            rank += (vj > vl) || (vj == vl && j < lane);
        }
        if (lane < K1 && rank < K2) sel2[rank] = sel1[lane];
    }
    __syncthreads();

    {
        int rows[K2];
        #pragma unroll
        for (int r = 0; r < K2; ++r) rows[r] = sel2[r]*CH;
        for (int c = tid; c < CH; c += NTHR) {
            float a0=0.f,a1=0.f;
            #pragma unroll
            for (int r = 0; r < K2; r += 2) { a0 += tok[rows[r]+c]; a1 += tok[rows[r+1]+c]; }
            sA[c] = (a0+a1) * (1.0f/K2) * g12[c];
        }
    }
    __syncthreads();

    if (wv == 0) {
        float s = 0.f, q = 0.f;
        #pragma unroll
        for (int k = 0; k < CH/64; ++k) {
            float v = sA[lane + k*64];
            s += v; q = fmaf(v, v, q);
        }
        s = wsum(s); q = wsum(q);
        if (lane == 0) {
            float mu  = s * (1.0f/CH);
            float var = q * (1.0f/CH) - mu*mu;
            scal[0] = mu;
            scal[1] = rsqrtf(var + 1e-5f);
        }
    }
    __syncthreads();

    if (wv < 5) {
        const float mu = scal[0], inv = scal[1];
        float acc = 0.f;
        #pragma unroll
        for (int k = 0; k < CH/64; ++k) {
            int c = lane + k*64;
            float nv = (sA[c] - mu) * inv * lng[c] + lnb[c];
            acc = fmaf(nv, cw[c*5 + wv], acc);
        }
        acc = wsum(acc);
        if (lane == 0) out[b*5 + wv] = acc + cb[wv];
    }
}

extern "C" void kernel_launch(void* const* d_in, const int* in_sizes, int n_in,
                              void* d_out, int out_size, void* d_ws, size_t ws_size,
                              hipStream_t stream) {
    (void)in_sizes; (void)n_in; (void)out_size;
    const float* x   = (const float*)d_in[0];
    const float* w1a = (const float*)d_in[1];
    const float* b1a = (const float*)d_in[2];
    const float* w2a = (const float*)d_in[3];
    const float* b2a = (const float*)d_in[4];
    const float* w1b = (const float*)d_in[5];
    const float* b1b = (const float*)d_in[6];
    const float* w2b = (const float*)d_in[7];
    const float* b2b = (const float*)d_in[8];
    const float* lng = (const float*)d_in[9];
    const float* lnb = (const float*)d_in[10];
    const float* cw  = (const float*)d_in[11];
    const float* cb  = (const float*)d_in[12];
    float* out = (float*)d_out;

    const size_t need = ((size_t)2*NB*CH + (size_t)NB*MID) * 4 + (size_t)NB*K1*4;
    if (ws_size < need) {
        // fallback: known-correct monolith
        hipLaunchKernelGGL(hier_se_fused, dim3(NB), dim3(NTHR), 0, stream,
                           x, w1a, b1a, w2a, b2a, w1b, b1b, w2b, b2b,
                           lng, lnb, cw, cb, out);
        return;
    }

    float* buf0 = (float*)d_ws;                   // colsum, later s2 (KB consumes colsum first)
    float* buf1 = buf0 + (size_t)NB*CH;           // g1, later g12 (in-place)
    float* hbuf = buf1 + (size_t)NB*CH;           // [2048,48]
    int*   sel1 = (int*)(hbuf + (size_t)NB*MID);  // [2048,36]

    hipLaunchKernelGGL(ka_colsum, dim3(NB), dim3(384), 0, stream, x, buf0);
    hipLaunchKernelGGL(kb_gemv1, dim3(NB/8), dim3(384), 0, stream,
                       buf0, w1a, b1a, hbuf, 1.0f/NTOK);
    hipLaunchKernelGGL(kc_gemv2, dim3(NB/32, 3), dim3(256), 0, stream,
                       hbuf, w2a, b2a, (const float*)nullptr, buf1);
    hipLaunchKernelGGL(kd_norm_select, dim3(NB), dim3(512), 0, stream,
                       x, buf1, buf0, sel1);
    hipLaunchKernelGGL(kb_gemv1, dim3(NB/8), dim3(384), 0, stream,
                       buf0, w1b, b1b, hbuf, 1.0f);
    hipLaunchKernelGGL(kc_gemv2, dim3(NB/32, 3), dim3(256), 0, stream,
                       hbuf, w2b, b2b, buf1, buf1);
    hipLaunchKernelGGL(kg_final, dim3(NB), dim3(512), 0, stream,
                       x, buf1, sel1, lng, lnb, cw, cb, out);
}

// Round 3
// 545.951 us; speedup vs baseline: 1.2592x; 1.2592x over previous
//
#include <hip/hip_runtime.h>
#include <math.h>

#define NB    2048
#define NTOK  49
#define CH    768
#define MID   48
#define K1    36
#define K2    24
#define NU1   (NTOK - K1)   // 13 unselected in round 1
#define NU2   (K1 - K2)     // 12 dropped in round 2
#define NTHR  384           // 6 waves

__device__ __forceinline__ float wsum(float v) {
    #pragma unroll
    for (int off = 32; off; off >>= 1) v += __shfl_xor(v, off, 64);
    return v;
}
__device__ __forceinline__ float gelu_exact(float v) {
    return 0.5f * v * (1.0f + erff(v * 0.70710678118654752440f));
}
__device__ __forceinline__ float sigmoidf(float v) {
    return 1.0f / (1.0f + expf(-v));
}

// One batch per block. No LDS staging of x (that capped the CU at 1 block and
// serialized 8 batches behind a 14-barrier chain). x[b] is read twice from
// global: pass 1 (colsum) from HBM, pass 2 (gated norms) hits L3 since it is
// temporally adjacent. Selected-row means use complement sums (13/12 rows
// instead of 36/24). Weights stream from L2 (same lines for every block).
__global__ __launch_bounds__(NTHR, 6)
void fused_all(const float* __restrict__ x,
               const float* __restrict__ w1a, const float* __restrict__ b1a,
               const float* __restrict__ w2a, const float* __restrict__ b2a,
               const float* __restrict__ w1b, const float* __restrict__ b1b,
               const float* __restrict__ w2b, const float* __restrict__ b2b,
               const float* __restrict__ lng, const float* __restrict__ lnb,
               const float* __restrict__ cw,  const float* __restrict__ cb,
               float* __restrict__ out)
{
    __shared__ float colsum[CH];     // colsum_all, later colsum_36 (in-place)
    __shared__ float sA[CH];         // s2, later pooled
    __shared__ float gv[CH];         // g1, later g12 (in-place)
    __shared__ float red[8 * MID];   // GEMV1 partials
    __shared__ float hb[MID];        // GEMV1 output
    __shared__ float ts[64];         // row scores (round 1: 49, round 2: 36)
    __shared__ int   sel1[K1];
    __shared__ int   unsel1[NU1];
    __shared__ int   unsel2[NU2];
    __shared__ float scal[2];

    const int tid  = threadIdx.x;
    const int lane = tid & 63;
    const int wv   = tid >> 6;
    const int b    = blockIdx.x;
    const float* xb = x + (size_t)b * (NTOK * CH);

    // ---- P1: column sums over 49 rows (float2 per thread, coalesced 512B/wave/row)
    {
        const float2* p = (const float2*)xb;   // row stride = 384 float2
        float sx = 0.f, sy = 0.f;
        #pragma unroll 7
        for (int n = 0; n < NTOK; ++n) {
            float2 v = p[n * 384 + tid];
            sx += v.x; sy += v.y;
        }
        colsum[2*tid]   = sx;
        colsum[2*tid+1] = sy;
    }
    __syncthreads();

    // ---- P2: h = gelu(colsum@W1a /49 + b1a). thread = (m = tid%48, chunk = tid/48)
    {
        const int m = tid % MID, ch = tid / MID;
        const float* wp = w1a + (ch * 96) * MID + m;
        const float* sp = colsum + ch * 96;
        float a = 0.f;
        #pragma unroll
        for (int k = 0; k < 96; ++k) a = fmaf(sp[k], wp[k * MID], a);
        red[ch * MID + m] = a;
    }
    __syncthreads();
    if (tid < MID) {
        float v = 0.f;
        #pragma unroll
        for (int c = 0; c < 8; ++c) v += red[c * MID + tid];
        hb[tid] = gelu_exact(v * (1.0f / NTOK) + b1a[tid]);
    }
    __syncthreads();

    // ---- P3: g1 = sigmoid(h@W2a + b2a), 2 cols/thread (float2)
    {
        const float2* w2r = (const float2*)w2a;        // row m: 384 float2
        float2 bb = ((const float2*)b2a)[tid];
        float a0 = bb.x, a1 = bb.y;
        #pragma unroll
        for (int m = 0; m < MID; ++m) {
            float2 w = w2r[(size_t)m * 384 + tid];
            float h = hb[m];
            a0 = fmaf(h, w.x, a0);
            a1 = fmaf(h, w.y, a1);
        }
        gv[2*tid]   = sigmoidf(a0);
        gv[2*tid+1] = sigmoidf(a1);
    }
    __syncthreads();

    // ---- P4: gated row norms, ts[n] = ||x_n * g1|| (rows striped over 6 waves)
    {
        float gs[12];
        #pragma unroll
        for (int k = 0; k < 3; ++k) {
            float4 q = *(const float4*)&gv[4*lane + 256*k];
            gs[4*k+0] = q.x*q.x; gs[4*k+1] = q.y*q.y;
            gs[4*k+2] = q.z*q.z; gs[4*k+3] = q.w*q.w;
        }
        for (int n = wv; n < NTOK; n += 6) {
            const float4* row = (const float4*)(xb + n * CH);
            float acc = 0.f;
            #pragma unroll
            for (int k = 0; k < 3; ++k) {
                float4 v = row[lane + 64*k];
                acc = fmaf(v.x*v.x, gs[4*k+0], acc);
                acc = fmaf(v.y*v.y, gs[4*k+1], acc);
                acc = fmaf(v.z*v.z, gs[4*k+2], acc);
                acc = fmaf(v.w*v.w, gs[4*k+3], acc);
            }
            acc = wsum(acc);
            if (lane == 0) ts[n] = sqrtf(acc);
        }
    }
    __syncthreads();

    // ---- P5: rank ts (softmax((ts-mu)/sd) is monotone in ts). top-36 + 13 complement.
    if (wv == 0) {
        float vl = (lane < NTOK) ? ts[lane] : -1.0f;
        int rank = 0;
        for (int j = 0; j < NTOK; ++j) {
            float vj = ts[j];
            rank += (vj > vl) || (vj == vl && j < lane);
        }
        if (lane < NTOK) {
            if (rank < K1) sel1[rank] = lane;       // rank order = jax top_k order
            else           unsel1[rank - K1] = lane;
        }
    }
    __syncthreads();

    // ---- P6: colsum36 = colsum - sum(13 unselected); s2 = g1 * colsum36/36
    {
        int rows[NU1];
        #pragma unroll
        for (int r = 0; r < NU1; ++r) rows[r] = unsel1[r] * CH;
        float2 cs = *(float2*)&colsum[2*tid];
        #pragma unroll
        for (int r = 0; r < NU1; ++r) {
            float2 v = *(const float2*)(xb + rows[r] + 2*tid);
            cs.x -= v.x; cs.y -= v.y;
        }
        *(float2*)&colsum[2*tid] = cs;             // now colsum_36
        float2 g = *(float2*)&gv[2*tid];
        sA[2*tid]   = cs.x * (1.0f / K1) * g.x;
        sA[2*tid+1] = cs.y * (1.0f / K1) * g.y;
    }
    __syncthreads();

    // ---- P7: h2 = gelu(s2@W1b + b1b)
    {
        const int m = tid % MID, ch = tid / MID;
        const float* wp = w1b + (ch * 96) * MID + m;
        const float* sp = sA + ch * 96;
        float a = 0.f;
        #pragma unroll
        for (int k = 0; k < 96; ++k) a = fmaf(sp[k], wp[k * MID], a);
        red[ch * MID + m] = a;
    }
    __syncthreads();
    if (tid < MID) {
        float v = 0.f;
        #pragma unroll
        for (int c = 0; c < 8; ++c) v += red[c * MID + tid];
        hb[tid] = gelu_exact(v + b1b[tid]);
    }
    __syncthreads();

    // ---- P8: g12 = g1 * sigmoid(h2@W2b + b2b)   (in-place on gv)
    {
        const float2* w2r = (const float2*)w2b;
        float2 bb = ((const float2*)b2b)[tid];
        float a0 = bb.x, a1 = bb.y;
        #pragma unroll
        for (int m = 0; m < MID; ++m) {
            float2 w = w2r[(size_t)m * 384 + tid];
            float h = hb[m];
            a0 = fmaf(h, w.x, a0);
            a1 = fmaf(h, w.y, a1);
        }
        gv[2*tid]   *= sigmoidf(a0);
        gv[2*tid+1] *= sigmoidf(a1);
    }
    __syncthreads();

    // ---- P9: round-2 gated norms on the 36 selected rows (6 per wave exactly)
    {
        float gr[12];
        #pragma unroll
        for (int k = 0; k < 3; ++k) {
            float4 q = *(const float4*)&gv[4*lane + 256*k];
            gr[4*k+0] = q.x*q.x; gr[4*k+1] = q.y*q.y;
            gr[4*k+2] = q.z*q.z; gr[4*k+3] = q.w*q.w;
        }
        for (int j = wv; j < K1; j += 6) {
            const float4* row = (const float4*)(xb + sel1[j] * CH);
            float acc = 0.f;
            #pragma unroll
            for (int k = 0; k < 3; ++k) {
                float4 v = row[lane + 64*k];
                acc = fmaf(v.x*v.x, gr[4*k+0], acc);
                acc = fmaf(v.y*v.y, gr[4*k+1], acc);
                acc = fmaf(v.z*v.z, gr[4*k+2], acc);
                acc = fmaf(v.w*v.w, gr[4*k+3], acc);
            }
            acc = wsum(acc);
            if (lane == 0) ts[j] = sqrtf(acc);
        }
    }
    __syncthreads();

    // ---- P10: rank 36 scores; keep the 12 DROPPED rows (complement pooling).
    //           tie index = round-1 rank position (matches ref top_k order).
    if (wv == 0) {
        float vl = (lane < K1) ? ts[lane] : -1.0f;
        int rank = 0;
        for (int j = 0; j < K1; ++j) {
            float vj = ts[j];
            rank += (vj > vl) || (vj == vl && j < lane);
        }
        if (lane < K1 && rank >= K2) unsel2[rank - K2] = sel1[lane];
    }
    __syncthreads();

    // ---- P11: pooled = g12 * (colsum36 - sum(12 dropped))/24  -> sA
    {
        int rows[NU2];
        #pragma unroll
        for (int r = 0; r < NU2; ++r) rows[r] = unsel2[r] * CH;
        float2 cs = *(float2*)&colsum[2*tid];
        #pragma unroll
        for (int r = 0; r < NU2; ++r) {
            float2 v = *(const float2*)(xb + rows[r] + 2*tid);
            cs.x -= v.x; cs.y -= v.y;
        }
        float2 g = *(float2*)&gv[2*tid];
        sA[2*tid]   = cs.x * (1.0f / K2) * g.x;
        sA[2*tid+1] = cs.y * (1.0f / K2) * g.y;
    }
    __syncthreads();

    // ---- P12: LayerNorm stats (ddof=0, eps=1e-5)
    if (wv == 0) {
        float s = 0.f, q = 0.f;
        #pragma unroll
        for (int k = 0; k < CH/64; ++k) {
            float v = sA[lane + 64*k];
            s += v; q = fmaf(v, v, q);
        }
        s = wsum(s); q = wsum(q);
        if (lane == 0) {
            float mu  = s * (1.0f / CH);
            float var = q * (1.0f / CH) - mu * mu;
            scal[0] = mu;
            scal[1] = rsqrtf(var + 1e-5f);
        }
    }
    __syncthreads();

    // ---- P13: out[b,k] = LN(pooled)@cls_w + cls_b  (wave k of 5)
    if (wv < 5) {
        const float mu = scal[0], inv = scal[1];
        float acc = 0.f;
        #pragma unroll
        for (int k = 0; k < CH/64; ++k) {
            int c = lane + 64*k;
            float nv = (sA[c] - mu) * inv * lng[c] + lnb[c];
            acc = fmaf(nv, cw[c*5 + wv], acc);
        }
        acc = wsum(acc);
        if (lane == 0) out[(size_t)b*5 + wv] = acc + cb[wv];
    }
}

extern "C" void kernel_launch(void* const* d_in, const int* in_sizes, int n_in,
                              void* d_out, int out_size, void* d_ws, size_t ws_size,
                              hipStream_t stream) {
    (void)in_sizes; (void)n_in; (void)out_size; (void)d_ws; (void)ws_size;
    const float* x   = (const float*)d_in[0];
    const float* w1a = (const float*)d_in[1];
    const float* b1a = (const float*)d_in[2];
    const float* w2a = (const float*)d_in[3];
    const float* b2a = (const float*)d_in[4];
    const float* w1b = (const float*)d_in[5];
    const float* b1b = (const float*)d_in[6];
    const float* w2b = (const float*)d_in[7];
    const float* b2b = (const float*)d_in[8];
    const float* lng = (const float*)d_in[9];
    const float* lnb = (const float*)d_in[10];
    const float* cw  = (const float*)d_in[11];
    const float* cb  = (const float*)d_in[12];
    float* out = (float*)d_out;

    hipLaunchKernelGGL(fused_all, dim3(NB), dim3(NTHR), 0, stream,
                       x, w1a, b1a, w2a, b2a, w1b, b1b, w2b, b2b,
                       lng, lnb, cw, cb, out);
}

// Round 4
// 527.279 us; speedup vs baseline: 1.3038x; 1.0354x over previous
//
#include <hip/hip_runtime.h>
#include <math.h>

#define NB    2048
#define NTOK  49
#define CH    768
#define MID   48
#define K1    36
#define K2    24
#define NU1   (NTOK - K1)   // 13 unselected in round 1
#define NU2   (K1 - K2)     // 12 dropped in round 2
#define NTHR  384           // 6 waves
#define BPB   2             // batches per block (phase-interleaved)

__device__ __forceinline__ float wsum(float v) {
    #pragma unroll
    for (int off = 32; off; off >>= 1) v += __shfl_xor(v, off, 64);
    return v;
}
__device__ __forceinline__ float gelu_exact(float v) {
    return 0.5f * v * (1.0f + erff(v * 0.70710678118654752440f));
}
__device__ __forceinline__ float sigmoidf(float v) {
    return 1.0f / (1.0f + expf(-v));
}

// Two batches per block, phase-interleaved: between every barrier pair we do
// batch-A work then batch-B work (independent -> loads/FMA chains overlap,
// 2x memory-level parallelism per phase), and each weight element is loaded
// once from L2 but feeds both batches. Barriers per batch halve vs round 3.
__global__ __launch_bounds__(NTHR, 4)
void fused2(const float* __restrict__ x,
            const float* __restrict__ w1a, const float* __restrict__ b1a,
            const float* __restrict__ w2a, const float* __restrict__ b2a,
            const float* __restrict__ w1b, const float* __restrict__ b1b,
            const float* __restrict__ w2b, const float* __restrict__ b2b,
            const float* __restrict__ lng, const float* __restrict__ lnb,
            const float* __restrict__ cw,  const float* __restrict__ cb,
            float* __restrict__ out)
{
    __shared__ float colsum[BPB][CH];   // colsum_all -> colsum_36 (in-place)
    __shared__ float sA[BPB][CH];       // s2, later pooled
    __shared__ float gv[BPB][CH];       // g1 -> g12 (in-place)
    __shared__ float red[BPB][8*MID];
    __shared__ float hb[BPB][MID];
    __shared__ float ts[BPB][64];
    __shared__ int   sel1[BPB][K1];
    __shared__ int   unsel1[BPB][NU1];
    __shared__ int   unsel2[BPB][NU2];
    __shared__ float scal[BPB][2];

    const int tid  = threadIdx.x;
    const int lane = tid & 63;
    const int wv   = tid >> 6;
    const int b0   = blockIdx.x * BPB;
    const float* xb0 = x + (size_t)b0 * (NTOK * CH);
    const float* xb1 = xb0 + (NTOK * CH);

    // ---- P1: column sums for both batches (98 independent float2 loads/thread)
    {
        const float2* pa = (const float2*)xb0;
        const float2* pb = (const float2*)xb1;
        float ax = 0.f, ay = 0.f, bx = 0.f, by = 0.f;
        #pragma unroll 7
        for (int n = 0; n < NTOK; ++n) {
            float2 va = pa[n * 384 + tid];
            float2 vb = pb[n * 384 + tid];
            ax += va.x; ay += va.y;
            bx += vb.x; by += vb.y;
        }
        colsum[0][2*tid] = ax; colsum[0][2*tid+1] = ay;
        colsum[1][2*tid] = bx; colsum[1][2*tid+1] = by;
    }
    __syncthreads();

    // ---- P2: h = gelu(colsum@W1a/49 + b1a); one w1 load feeds both batches
    {
        const int m = tid % MID, ch = tid / MID;
        const float* wp = w1a + (ch * 96) * MID + m;
        const float* s0 = &colsum[0][ch * 96];
        const float* s1 = &colsum[1][ch * 96];
        float a0 = 0.f, a1 = 0.f;
        #pragma unroll
        for (int k = 0; k < 96; ++k) {
            float w = wp[k * MID];
            a0 = fmaf(s0[k], w, a0);
            a1 = fmaf(s1[k], w, a1);
        }
        red[0][ch * MID + m] = a0;
        red[1][ch * MID + m] = a1;
    }
    __syncthreads();
    if (tid < BPB * MID) {
        const int bi = tid / MID, m = tid % MID;
        float v = 0.f;
        #pragma unroll
        for (int c = 0; c < 8; ++c) v += red[bi][c * MID + m];
        hb[bi][m] = gelu_exact(v * (1.0f / NTOK) + b1a[m]);
    }
    __syncthreads();

    // ---- P3: g1 = sigmoid(h@W2a + b2a); shared w2 loads
    {
        const float2* w2r = (const float2*)w2a;
        float2 bb = ((const float2*)b2a)[tid];
        float a0x = bb.x, a0y = bb.y, a1x = bb.x, a1y = bb.y;
        #pragma unroll
        for (int m = 0; m < MID; ++m) {
            float2 w = w2r[(size_t)m * 384 + tid];
            float h0 = hb[0][m], h1 = hb[1][m];
            a0x = fmaf(h0, w.x, a0x); a0y = fmaf(h0, w.y, a0y);
            a1x = fmaf(h1, w.x, a1x); a1y = fmaf(h1, w.y, a1y);
        }
        gv[0][2*tid] = sigmoidf(a0x); gv[0][2*tid+1] = sigmoidf(a0y);
        gv[1][2*tid] = sigmoidf(a1x); gv[1][2*tid+1] = sigmoidf(a1y);
    }
    __syncthreads();

    // ---- P4: gated row norms for both batches (L3-warm x re-read)
    #pragma unroll
    for (int bi = 0; bi < BPB; ++bi) {
        const float* xb = bi ? xb1 : xb0;
        float gs[12];
        #pragma unroll
        for (int k = 0; k < 3; ++k) {
            float4 q = *(const float4*)&gv[bi][4*lane + 256*k];
            gs[4*k+0] = q.x*q.x; gs[4*k+1] = q.y*q.y;
            gs[4*k+2] = q.z*q.z; gs[4*k+3] = q.w*q.w;
        }
        for (int n = wv; n < NTOK; n += 6) {
            const float4* row = (const float4*)(xb + n * CH);
            float acc = 0.f;
            #pragma unroll
            for (int k = 0; k < 3; ++k) {
                float4 v = row[lane + 64*k];
                acc = fmaf(v.x*v.x, gs[4*k+0], acc);
                acc = fmaf(v.y*v.y, gs[4*k+1], acc);
                acc = fmaf(v.z*v.z, gs[4*k+2], acc);
                acc = fmaf(v.w*v.w, gs[4*k+3], acc);
            }
            acc = wsum(acc);
            if (lane == 0) ts[bi][n] = sqrtf(acc);
        }
    }
    __syncthreads();

    // ---- P5: rank (softmax((ts-mu)/sd) monotone in ts). wave bi ranks batch bi.
    if (wv < BPB) {
        const int bi = wv;
        float vl = (lane < NTOK) ? ts[bi][lane] : -1.0f;
        int rank = 0;
        for (int j = 0; j < NTOK; ++j) {
            float vj = ts[bi][j];
            rank += (vj > vl) || (vj == vl && j < lane);
        }
        if (lane < NTOK) {
            if (rank < K1) sel1[bi][rank] = lane;       // rank order = jax top_k order
            else           unsel1[bi][rank - K1] = lane;
        }
    }
    __syncthreads();

    // ---- P6: colsum36 = colsum - sum(13 unsel); s2 = g1 * colsum36/36
    #pragma unroll
    for (int bi = 0; bi < BPB; ++bi) {
        const float* xb = bi ? xb1 : xb0;
        int rows[NU1];
        #pragma unroll
        for (int r = 0; r < NU1; ++r) rows[r] = unsel1[bi][r] * CH;
        float2 cs = *(float2*)&colsum[bi][2*tid];
        #pragma unroll
        for (int r = 0; r < NU1; ++r) {
            float2 v = *(const float2*)(xb + rows[r] + 2*tid);
            cs.x -= v.x; cs.y -= v.y;
        }
        *(float2*)&colsum[bi][2*tid] = cs;              // now colsum_36
        float2 g = *(float2*)&gv[bi][2*tid];
        sA[bi][2*tid]   = cs.x * (1.0f / K1) * g.x;
        sA[bi][2*tid+1] = cs.y * (1.0f / K1) * g.y;
    }
    __syncthreads();

    // ---- P7: h2 = gelu(s2@W1b + b1b)
    {
        const int m = tid % MID, ch = tid / MID;
        const float* wp = w1b + (ch * 96) * MID + m;
        const float* s0 = &sA[0][ch * 96];
        const float* s1 = &sA[1][ch * 96];
        float a0 = 0.f, a1 = 0.f;
        #pragma unroll
        for (int k = 0; k < 96; ++k) {
            float w = wp[k * MID];
            a0 = fmaf(s0[k], w, a0);
            a1 = fmaf(s1[k], w, a1);
        }
        red[0][ch * MID + m] = a0;
        red[1][ch * MID + m] = a1;
    }
    __syncthreads();
    if (tid < BPB * MID) {
        const int bi = tid / MID, m = tid % MID;
        float v = 0.f;
        #pragma unroll
        for (int c = 0; c < 8; ++c) v += red[bi][c * MID + m];
        hb[bi][m] = gelu_exact(v + b1b[m]);
    }
    __syncthreads();

    // ---- P8: g12 = g1 * sigmoid(h2@W2b + b2b)  (in-place on gv)
    {
        const float2* w2r = (const float2*)w2b;
        float2 bb = ((const float2*)b2b)[tid];
        float a0x = bb.x, a0y = bb.y, a1x = bb.x, a1y = bb.y;
        #pragma unroll
        for (int m = 0; m < MID; ++m) {
            float2 w = w2r[(size_t)m * 384 + tid];
            float h0 = hb[0][m], h1 = hb[1][m];
            a0x = fmaf(h0, w.x, a0x); a0y = fmaf(h0, w.y, a0y);
            a1x = fmaf(h1, w.x, a1x); a1y = fmaf(h1, w.y, a1y);
        }
        gv[0][2*tid]   *= sigmoidf(a0x); gv[0][2*tid+1] *= sigmoidf(a0y);
        gv[1][2*tid]   *= sigmoidf(a1x); gv[1][2*tid+1] *= sigmoidf(a1y);
    }
    __syncthreads();

    // ---- P9: round-2 gated norms on the 36 selected rows
    #pragma unroll
    for (int bi = 0; bi < BPB; ++bi) {
        const float* xb = bi ? xb1 : xb0;
        float gr[12];
        #pragma unroll
        for (int k = 0; k < 3; ++k) {
            float4 q = *(const float4*)&gv[bi][4*lane + 256*k];
            gr[4*k+0] = q.x*q.x; gr[4*k+1] = q.y*q.y;
            gr[4*k+2] = q.z*q.z; gr[4*k+3] = q.w*q.w;
        }
        for (int j = wv; j < K1; j += 6) {
            const float4* row = (const float4*)(xb + sel1[bi][j] * CH);
            float acc = 0.f;
            #pragma unroll
            for (int k = 0; k < 3; ++k) {
                float4 v = row[lane + 64*k];
                acc = fmaf(v.x*v.x, gr[4*k+0], acc);
                acc = fmaf(v.y*v.y, gr[4*k+1], acc);
                acc = fmaf(v.z*v.z, gr[4*k+2], acc);
                acc = fmaf(v.w*v.w, gr[4*k+3], acc);
            }
            acc = wsum(acc);
            if (lane == 0) ts[bi][j] = sqrtf(acc);
        }
    }
    __syncthreads();

    // ---- P10: rank 36; keep the 12 DROPPED rows (complement pooling)
    if (wv < BPB) {
        const int bi = wv;
        float vl = (lane < K1) ? ts[bi][lane] : -1.0f;
        int rank = 0;
        for (int j = 0; j < K1; ++j) {
            float vj = ts[bi][j];
            rank += (vj > vl) || (vj == vl && j < lane);
        }
        if (lane < K1 && rank >= K2) unsel2[bi][rank - K2] = sel1[bi][lane];
    }
    __syncthreads();

    // ---- P11: pooled = g12 * (colsum36 - sum(12 dropped))/24 -> sA
    #pragma unroll
    for (int bi = 0; bi < BPB; ++bi) {
        const float* xb = bi ? xb1 : xb0;
        int rows[NU2];
        #pragma unroll
        for (int r = 0; r < NU2; ++r) rows[r] = unsel2[bi][r] * CH;
        float2 cs = *(float2*)&colsum[bi][2*tid];
        #pragma unroll
        for (int r = 0; r < NU2; ++r) {
            float2 v = *(const float2*)(xb + rows[r] + 2*tid);
            cs.x -= v.x; cs.y -= v.y;
        }
        float2 g = *(float2*)&gv[bi][2*tid];
        sA[bi][2*tid]   = cs.x * (1.0f / K2) * g.x;
        sA[bi][2*tid+1] = cs.y * (1.0f / K2) * g.y;
    }
    __syncthreads();

    // ---- P12: LayerNorm stats (ddof=0, eps=1e-5); wave bi does batch bi
    if (wv < BPB) {
        const int bi = wv;
        float s = 0.f, q = 0.f;
        #pragma unroll
        for (int k = 0; k < CH/64; ++k) {
            float v = sA[bi][lane + 64*k];
            s += v; q = fmaf(v, v, q);
        }
        s = wsum(s); q = wsum(q);
        if (lane == 0) {
            float mu  = s * (1.0f / CH);
            float var = q * (1.0f / CH) - mu * mu;
            scal[bi][0] = mu;
            scal[bi][1] = rsqrtf(var + 1e-5f);
        }
    }
    __syncthreads();

    // ---- P13: out = LN(pooled)@cls_w + cls_b; 10 (batch,k) tasks over 6 waves
    for (int t = wv; t < BPB * 5; t += 6) {
        const int bi = t / 5, k5 = t % 5;
        const float mu = scal[bi][0], inv = scal[bi][1];
        float acc = 0.f;
        #pragma unroll
        for (int k = 0; k < CH/64; ++k) {
            int c = lane + 64*k;
            float nv = (sA[bi][c] - mu) * inv * lng[c] + lnb[c];
            acc = fmaf(nv, cw[c*5 + k5], acc);
        }
        acc = wsum(acc);
        if (lane == 0) out[(size_t)(b0 + bi)*5 + k5] = acc + cb[k5];
    }
}

extern "C" void kernel_launch(void* const* d_in, const int* in_sizes, int n_in,
                              void* d_out, int out_size, void* d_ws, size_t ws_size,
                              hipStream_t stream) {
    (void)in_sizes; (void)n_in; (void)out_size; (void)d_ws; (void)ws_size;
    const float* x   = (const float*)d_in[0];
    const float* w1a = (const float*)d_in[1];
    const float* b1a = (const float*)d_in[2];
    const float* w2a = (const float*)d_in[3];
    const float* b2a = (const float*)d_in[4];
    const float* w1b = (const float*)d_in[5];
    const float* b1b = (const float*)d_in[6];
    const float* w2b = (const float*)d_in[7];
    const float* b2b = (const float*)d_in[8];
    const float* lng = (const float*)d_in[9];
    const float* lnb = (const float*)d_in[10];
    const float* cw  = (const float*)d_in[11];
    const float* cb  = (const float*)d_in[12];
    float* out = (float*)d_out;

    hipLaunchKernelGGL(fused2, dim3(NB / BPB), dim3(NTHR), 0, stream,
                       x, w1a, b1a, w2a, b2a, w1b, b1b, w2b, b2b,
                       lng, lnb, cw, cb, out);
}